// Round 10
// baseline (1287.960 us; speedup 1.0000x reference)
//
#include <hip/hip_runtime.h>

typedef unsigned short u16;
typedef unsigned int u32;
typedef _Float16 f16;

using half8 = __attribute__((ext_vector_type(8))) _Float16;
using f32x4 = __attribute__((ext_vector_type(4))) float;

__device__ __forceinline__ void async16(const void* g, void* l) {
    __builtin_amdgcn_global_load_lds(
        (const __attribute__((address_space(1))) u32*)g,
        (__attribute__((address_space(3))) u32*)l, 16, 0, 0);
}

// ---------------------------------------------------------------------------
// Prep 1: P1 = feats @ W1a (fp32, Qc folded later), P2h = f16(feats @ W1b)
// ---------------------------------------------------------------------------
__global__ __launch_bounds__(512) void prep_p12(const float* __restrict__ img,
                                                const float* __restrict__ gw1,
                                                float* __restrict__ P1,
                                                f16* __restrict__ P2h) {
    const int blk = blockIdx.x;
    const int n = blk >> 3;
    const int c0 = (blk & 7) * 8;
    const int t = threadIdx.x;
    __shared__ float feats[8][68];
    for (int idx = t; idx < 8 * 66; idx += 512) {
        int rr = idx / 66, cc = idx % 66, cell = c0 + rr;
        float v;
        if (cc < 64)       v = img[((size_t)(n * 64 + cc)) * 64 + cell];
        else if (cc == 64) v = (float)(cell >> 3);
        else               v = (float)(cell & 7);
        feats[rr][cc] = v;
    }
    __syncthreads();
    const int g = t;
    float a1[8], a2[8];
#pragma unroll
    for (int r = 0; r < 8; ++r) { a1[r] = 0.f; a2[r] = 0.f; }
    for (int c = 0; c < 66; ++c) {
        float wa = gw1[(size_t)c * 512 + g];
        float wb = gw1[(size_t)(66 + c) * 512 + g];
#pragma unroll
        for (int r = 0; r < 8; ++r) {
            a1[r] += feats[r][c] * wa;
            a2[r] += feats[r][c] * wb;
        }
    }
#pragma unroll
    for (int r = 0; r < 8; ++r) {
        P1[((size_t)(n * 64 + c0 + r)) * 512 + g] = a1[r];
        P2h[((size_t)(n * 64 + c0 + r)) * 512 + g] = (f16)a2[r];
    }
}

// ---------------------------------------------------------------------------
// Prep 2: Qc[n] = ques[n] @ W1c + b1; P1h = f16(P1 + Qc). Also zero Ctx.
// grid 64, block 512.
// ---------------------------------------------------------------------------
__global__ __launch_bounds__(512) void prep_q2(const float* __restrict__ ques,
                                               const float* __restrict__ gw1,
                                               const float* __restrict__ gb1,
                                               const float* __restrict__ P1,
                                               f16* __restrict__ P1h,
                                               float* __restrict__ Ctx) {
    const int n = blockIdx.x;
    const int t = threadIdx.x;
    __shared__ float q[256];
    if (t < 256) q[t] = ques[(size_t)n * 256 + t];
    __syncthreads();
    float acc = gb1[t];
    for (int e = 0; e < 256; ++e)
        acc += q[e] * gw1[(size_t)(132 + e) * 512 + t];
    const float* src = P1 + (((size_t)(n * 64)) << 9) + t;
    f16* dst = P1h + (((size_t)(n * 64)) << 9) + t;
    for (int r = 0; r < 64; ++r)
        dst[(size_t)r * 512] = (f16)(src[(size_t)r * 512] + acc);
    Ctx[(size_t)n * 512 + t] = 0.f;
}

// ---------------------------------------------------------------------------
// Prep 3: transpose W2/W3/W4 (512x512 fp32 [k][n] -> fp16 [n][k])
// ---------------------------------------------------------------------------
__global__ void transpose_w(const float* __restrict__ W2, const float* __restrict__ W3,
                            const float* __restrict__ W4, f16* __restrict__ T2,
                            f16* __restrict__ T3, f16* __restrict__ T4) {
    const int L = blockIdx.z;
    const float* W = (L == 0) ? W2 : ((L == 1) ? W3 : W4);
    f16* T = (L == 0) ? T2 : ((L == 1) ? T3 : T4);
    __shared__ float tile[32][33];
    const int bx = blockIdx.x * 32;  // n origin
    const int by = blockIdx.y * 32;  // k origin
    const int tx = threadIdx.x, ty = threadIdx.y;
    for (int r = ty; r < 32; r += 8)
        tile[r][tx] = W[(size_t)(by + r) * 512 + bx + tx];
    __syncthreads();
    for (int r = ty; r < 32; r += 8)
        T[(size_t)(bx + r) * 512 + by + tx] = (f16)tile[tx][r];
}

// ---------------------------------------------------------------------------
// Fused construct + layer-2 GEMM: C(256x128) = relu(H1tile @ T2 + b2) -> H2.
// A-tile rows = relu(P1h[nb,ii] + P2h[nb,jj]) built from F16 tables (2x16B
// loads + 8 f16 add/max per granule, no cvt) into swizzled LDS slots
// (phys == linear p). B staged first via async16 so DMA overlaps VALU.
// 256x128 / BK=64 / XCD-pinned (round-7-proven frame), 3 blocks/CU.
// ---------------------------------------------------------------------------
__global__ __launch_bounds__(256, 3) void gemm2c(
    const f16* __restrict__ P1h, const f16* __restrict__ P2h,
    const f16* __restrict__ Bt, const float* __restrict__ bias,
    f16* __restrict__ Out, int row_base) {
    const int tid = threadIdx.x;
    const int lane = tid & 63;
    const int quad = lane >> 4;
    const int l15 = lane & 15;
    const int wv = tid >> 6;
    const int wm = wv >> 1, wn = wv & 1;
    const int b  = blockIdx.x;
    const int x  = b & 7;
    const int s  = b >> 3;
    const int bn = s & 3;
    const int bm = (s >> 2) * 8 + x;     // 0..255

    __shared__ alignas(16) f16 lA[256 * 64];   // 32 KB
    __shared__ alignas(16) f16 lB[128 * 64];   // 16 KB

    const int p0 = row_base + bm * 256;        // global pair index of row 0
    const int nb = p0 >> 12;                   // batch index
    const f16* P1b = P1h + (((size_t)(nb * 64)) << 9);
    const f16* P2b = P2h + (((size_t)(nb * 64)) << 9);

    f32x4 acc[8][4];
#pragma unroll
    for (int mi = 0; mi < 8; ++mi)
#pragma unroll
        for (int ni = 0; ni < 4; ++ni)
            acc[mi][ni] = (f32x4){0.f, 0.f, 0.f, 0.f};

    for (int kt = 0; kt < 8; ++kt) {
        const int k0 = kt * 64;
        // ---- stage B first (async DMA overlaps VALU construct below) ----
#pragma unroll
        for (int c = 0; c < 4; ++c) {
            int p = c * 256 + tid;
            int r = p >> 3;
            int gc = ((p & 7) - r) & 7;
            const f16* srcB = Bt + (((size_t)(bn * 128 + r)) << 9) + k0 + gc * 8;
            async16(srcB, &lB[(c * 256 + (tid & ~63)) * 8]);
        }
        // ---- construct A-tile granules (f16 adds) -> LDS ----
#pragma unroll
        for (int c = 0; c < 8; ++c) {
            int p = c * 256 + tid;
            int r = p >> 3;                       // row 0..255
            int gc = ((p & 7) - r) & 7;
            int k = k0 + gc * 8;
            int ii = ((bm * 4) + (r >> 6)) & 63;
            int jj = r & 63;
            half8 xx = *(const half8*)(P1b + (((size_t)ii) << 9) + k);
            half8 yy = *(const half8*)(P2b + (((size_t)jj) << 9) + k);
            half8 hv;
#pragma unroll
            for (int e = 0; e < 8; ++e) {
                f16 sv = (f16)(xx[e] + yy[e]);
                hv[e] = sv > (f16)0 ? sv : (f16)0;
            }
            *(half8*)&lA[p * 8] = hv;
        }
        __syncthreads();
#pragma unroll
        for (int ks = 0; ks < 2; ++ks) {
            half8 af[8], bf[4];
            const int gc = ks * 4 + quad;
#pragma unroll
            for (int mi = 0; mi < 8; ++mi) {
                int r = wm * 128 + mi * 16 + l15;
                af[mi] = *(const half8*)&lA[(r * 8 + ((gc + r) & 7)) * 8];
            }
#pragma unroll
            for (int ni = 0; ni < 4; ++ni) {
                int r = wn * 64 + ni * 16 + l15;
                bf[ni] = *(const half8*)&lB[(r * 8 + ((gc + r) & 7)) * 8];
            }
#pragma unroll
            for (int mi = 0; mi < 8; ++mi)
#pragma unroll
                for (int ni = 0; ni < 4; ++ni)
                    acc[mi][ni] = __builtin_amdgcn_mfma_f32_16x16x32_f16(
                        af[mi], bf[ni], acc[mi][ni], 0, 0, 0);
        }
        __syncthreads();
    }

#pragma unroll
    for (int mi = 0; mi < 8; ++mi) {
#pragma unroll
        for (int ni = 0; ni < 4; ++ni) {
            int col = bn * 128 + wn * 64 + ni * 16 + l15;
            float bb = bias[col];
#pragma unroll
            for (int rr = 0; rr < 4; ++rr) {
                int row = bm * 256 + wm * 128 + mi * 16 + quad * 4 + rr;
                float v = fmaxf(acc[mi][ni][rr] + bb, 0.f);
                Out[(((size_t)row) << 9) + col] = (f16)v;
            }
        }
    }
}

// ---------------------------------------------------------------------------
// GEMM (round-7-proven): C(256x128) = relu(A @ B + bias). 4 waves, wave-tile
// 128x64, BK=64, XCD-pinned (bn fast within stripe, stripe%8=XCD), 3 blk/CU.
// Granule swizzle: phys = r*8 + ((gc + r)&7); 2-way-max bank aliasing.
// REDUCE: shfl-butterfly row-sum of relu -> lsum -> Ctx atomics (mean num).
// ---------------------------------------------------------------------------
template <bool REDUCE>
__global__ __launch_bounds__(256, 3) void gemm_kernel(
    const f16* __restrict__ Ain, const f16* __restrict__ Bt,
    const float* __restrict__ bias, f16* __restrict__ Out,
    float* __restrict__ Ctx, int row_base) {
    const int tid = threadIdx.x;
    const int lane = tid & 63;
    const int quad = lane >> 4;
    const int l15 = lane & 15;
    const int wv = tid >> 6;
    const int wm = wv >> 1, wn = wv & 1;
    const int b  = blockIdx.x;
    const int x  = b & 7;
    const int s  = b >> 3;
    const int bn = s & 3;
    const int bm = (s >> 2) * 8 + x;     // 0..255

    __shared__ alignas(16) f16 lA[256 * 64];   // 32 KB
    __shared__ alignas(16) f16 lB[128 * 64];   // 16 KB
    __shared__ float lsum[128];

    if (REDUCE && tid < 128) lsum[tid] = 0.f;

    f32x4 acc[8][4];
#pragma unroll
    for (int mi = 0; mi < 8; ++mi)
#pragma unroll
        for (int ni = 0; ni < 4; ++ni)
            acc[mi][ni] = (f32x4){0.f, 0.f, 0.f, 0.f};

    for (int kt = 0; kt < 8; ++kt) {
        const int k0 = kt * 64;
#pragma unroll
        for (int c = 0; c < 8; ++c) {
            int p = c * 256 + tid;
            int r = p >> 3;
            int gc = ((p & 7) - r) & 7;
            const f16* srcA = Ain + (((size_t)(bm * 256 + r)) << 9) + k0 + gc * 8;
            async16(srcA, &lA[(c * 256 + (tid & ~63)) * 8]);
        }
#pragma unroll
        for (int c = 0; c < 4; ++c) {
            int p = c * 256 + tid;
            int r = p >> 3;
            int gc = ((p & 7) - r) & 7;
            const f16* srcB = Bt + (((size_t)(bn * 128 + r)) << 9) + k0 + gc * 8;
            async16(srcB, &lB[(c * 256 + (tid & ~63)) * 8]);
        }
        __syncthreads();
#pragma unroll
        for (int ks = 0; ks < 2; ++ks) {
            half8 af[8], bf[4];
            const int gc = ks * 4 + quad;
#pragma unroll
            for (int mi = 0; mi < 8; ++mi) {
                int r = wm * 128 + mi * 16 + l15;
                af[mi] = *(const half8*)&lA[(r * 8 + ((gc + r) & 7)) * 8];
            }
#pragma unroll
            for (int ni = 0; ni < 4; ++ni) {
                int r = wn * 64 + ni * 16 + l15;
                bf[ni] = *(const half8*)&lB[(r * 8 + ((gc + r) & 7)) * 8];
            }
#pragma unroll
            for (int mi = 0; mi < 8; ++mi)
#pragma unroll
                for (int ni = 0; ni < 4; ++ni)
                    acc[mi][ni] = __builtin_amdgcn_mfma_f32_16x16x32_f16(
                        af[mi], bf[ni], acc[mi][ni], 0, 0, 0);
        }
        __syncthreads();
    }

    if (!REDUCE) {
#pragma unroll
        for (int mi = 0; mi < 8; ++mi) {
#pragma unroll
            for (int ni = 0; ni < 4; ++ni) {
                int col = bn * 128 + wn * 64 + ni * 16 + l15;
                float bb = bias[col];
#pragma unroll
                for (int rr = 0; rr < 4; ++rr) {
                    int row = bm * 256 + wm * 128 + mi * 16 + quad * 4 + rr;
                    float v = fmaxf(acc[mi][ni][rr] + bb, 0.f);
                    Out[(((size_t)row) << 9) + col] = (f16)v;
                }
            }
        }
    } else {
#pragma unroll
        for (int ni = 0; ni < 4; ++ni) {
            int coll = wn * 64 + ni * 16 + l15;
            float bb = bias[bn * 128 + coll];
            float ssum = 0.f;
#pragma unroll
            for (int mi = 0; mi < 8; ++mi)
#pragma unroll
                for (int rr = 0; rr < 4; ++rr)
                    ssum += fmaxf(acc[mi][ni][rr] + bb, 0.f);
            ssum += __shfl_xor(ssum, 16, 64);
            ssum += __shfl_xor(ssum, 32, 64);
            if (quad == 0) atomicAdd(&lsum[coll], ssum);
        }
        __syncthreads();
        if (tid < 128) {
            int nb = (row_base + bm * 256) >> 12;
            atomicAdd(&Ctx[(((size_t)nb) << 9) + bn * 128 + tid], lsum[tid]);
        }
    }
}

// ---------------------------------------------------------------------------
// f-MLP layer: Out[n, cs*128..+128) = relu(In[n,:]*scale @ W + b).
// grid (64, 4), block 512 = 128 cols x 4 k-segments.
// ---------------------------------------------------------------------------
__global__ __launch_bounds__(512) void fmlp_layer(
    const float* __restrict__ In, const float* __restrict__ Wt,
    const float* __restrict__ bias, float* __restrict__ Out, float scale) {
    const int n = blockIdx.x, cs = blockIdx.y;
    const int t = threadIdx.x;
    const int col = cs * 128 + (t & 127);
    const int seg = t >> 7;
    __shared__ float a[512];
    __shared__ float red[512];
    a[t] = In[(size_t)n * 512 + t] * scale;
    __syncthreads();
    float p = 0.f;
#pragma unroll 4
    for (int i = seg * 128; i < seg * 128 + 128; ++i)
        p += a[i] * Wt[(size_t)i * 512 + col];
    red[t] = p;
    __syncthreads();
    if (t < 128) {
        float v = red[t] + red[t + 128] + red[t + 256] + red[t + 384] + bias[col];
        Out[(size_t)n * 512 + cs * 128 + t] = fmaxf(v, 0.f);
    }
}

// ---------------------------------------------------------------------------
// Final logits + log_softmax. grid 64, block 64 (one wave per batch row).
// ---------------------------------------------------------------------------
__global__ __launch_bounds__(64) void fmlp_out(
    const float* __restrict__ A2, const float* __restrict__ fw3,
    const float* __restrict__ fb3, float* __restrict__ out) {
    const int n = blockIdx.x;
    const int lane = threadIdx.x;
    float s0 = 0.f, s1 = 0.f;
    for (int i = lane; i < 512; i += 64) {
        float v = A2[(size_t)n * 512 + i];
        s0 += v * fw3[i * 2];
        s1 += v * fw3[i * 2 + 1];
    }
#pragma unroll
    for (int d = 1; d < 64; d <<= 1) {
        s0 += __shfl_xor(s0, d, 64);
        s1 += __shfl_xor(s1, d, 64);
    }
    if (lane == 0) {
        s0 += fb3[0];
        s1 += fb3[1];
        float m = fmaxf(s0, s1);
        float l = logf(expf(s0 - m) + expf(s1 - m)) + m;
        out[n * 2 + 0] = s0 - l;
        out[n * 2 + 1] = s1 - l;
    }
}

// ---------------------------------------------------------------------------
extern "C" void kernel_launch(void* const* d_in, const int* in_sizes, int n_in,
                              void* d_out, int out_size, void* d_ws, size_t ws_size,
                              hipStream_t stream) {
    const float* img  = (const float*)d_in[0];
    const float* ques = (const float*)d_in[1];
    const float* gw1  = (const float*)d_in[2];
    const float* gb1  = (const float*)d_in[3];
    const float* gw2  = (const float*)d_in[4];
    const float* gb2  = (const float*)d_in[5];
    const float* gw3  = (const float*)d_in[6];
    const float* gb3  = (const float*)d_in[7];
    const float* gw4  = (const float*)d_in[8];
    const float* gb4  = (const float*)d_in[9];
    const float* fw1  = (const float*)d_in[10];
    const float* fb1  = (const float*)d_in[11];
    const float* fw2  = (const float*)d_in[12];
    const float* fb2  = (const float*)d_in[13];
    const float* fw3  = (const float*)d_in[14];
    const float* fb3  = (const float*)d_in[15];

    char* ws = (char*)d_ws;
    size_t off = 0;
    float* P1  = (float*)(ws + off); off += (size_t)4096 * 512 * 4;   // 8 MB fp32 scratch
    f16* P1h = (f16*)(ws + off); off += (size_t)4096 * 512 * 2;       // 4 MB (P1+Qc, f16)
    f16* P2h = (f16*)(ws + off); off += (size_t)4096 * 512 * 2;       // 4 MB
    float* Ctx = (float*)(ws + off); off += (size_t)64 * 512 * 4;
    float* Z1  = (float*)(ws + off); off += (size_t)64 * 512 * 4;
    float* Z2  = (float*)(ws + off); off += (size_t)64 * 512 * 4;
    f16* T2 = (f16*)(ws + off); off += (size_t)512 * 512 * 2;
    f16* T3 = (f16*)(ws + off); off += (size_t)512 * 512 * 2;
    f16* T4 = (f16*)(ws + off); off += (size_t)512 * 512 * 2;
    const int MCH = 65536;                                            // rows/chunk
    f16* HA = (f16*)(ws + off); off += (size_t)MCH * 512 * 2;         // 67 MB
    f16* HB = (f16*)(ws + off); off += (size_t)MCH * 512 * 2;         // 67 MB

    prep_p12<<<512, 512, 0, stream>>>(img, gw1, P1, P2h);
    prep_q2<<<64, 512, 0, stream>>>(ques, gw1, gb1, P1, P1h, Ctx);
    transpose_w<<<dim3(16, 16, 3), dim3(32, 8), 0, stream>>>(gw2, gw3, gw4, T2, T3, T4);

    const int ggrid = (MCH / 256) * 4;       // 1024 blocks per GEMM dispatch
    for (int ch = 0; ch < 262144 / MCH; ++ch) {
        int row_base = ch * MCH;
        gemm2c<<<ggrid, 256, 0, stream>>>(P1h, P2h, T2, gb2, HB, row_base);
        gemm_kernel<false><<<ggrid, 256, 0, stream>>>(HB, T3, gb3, HA, nullptr, row_base);
        gemm_kernel<true ><<<ggrid, 256, 0, stream>>>(HA, T4, gb4, nullptr, Ctx, row_base);
    }

    fmlp_layer<<<dim3(64, 4), 512, 0, stream>>>(Ctx, fw1, fb1, Z1, 1.0f / 4096.0f);
    fmlp_layer<<<dim3(64, 4), 512, 0, stream>>>(Z1, fw2, fb2, Z2, 1.0f);
    fmlp_out<<<64, 64, 0, stream>>>(Z2, fw3, fb3, (float*)d_out);
}

// Round 11
// 658.754 us; speedup vs baseline: 1.9551x; 1.9551x over previous
//
#include <hip/hip_runtime.h>

typedef unsigned short u16;
typedef unsigned int u32;
typedef _Float16 f16;

using half8 = __attribute__((ext_vector_type(8))) _Float16;
using f32x4 = __attribute__((ext_vector_type(4))) float;

__device__ __forceinline__ void async16(const void* g, void* l) {
    __builtin_amdgcn_global_load_lds(
        (const __attribute__((address_space(1))) u32*)g,
        (__attribute__((address_space(3))) u32*)l, 16, 0, 0);
}

// ---------------------------------------------------------------------------
// Prep 1: P1 = feats @ W1a (fp32, Qc folded later), P2h = f16(feats @ W1b)
// ---------------------------------------------------------------------------
__global__ __launch_bounds__(512) void prep_p12(const float* __restrict__ img,
                                                const float* __restrict__ gw1,
                                                float* __restrict__ P1,
                                                f16* __restrict__ P2h) {
    const int blk = blockIdx.x;
    const int n = blk >> 3;
    const int c0 = (blk & 7) * 8;
    const int t = threadIdx.x;
    __shared__ float feats[8][68];
    for (int idx = t; idx < 8 * 66; idx += 512) {
        int rr = idx / 66, cc = idx % 66, cell = c0 + rr;
        float v;
        if (cc < 64)       v = img[((size_t)(n * 64 + cc)) * 64 + cell];
        else if (cc == 64) v = (float)(cell >> 3);
        else               v = (float)(cell & 7);
        feats[rr][cc] = v;
    }
    __syncthreads();
    const int g = t;
    float a1[8], a2[8];
#pragma unroll
    for (int r = 0; r < 8; ++r) { a1[r] = 0.f; a2[r] = 0.f; }
    for (int c = 0; c < 66; ++c) {
        float wa = gw1[(size_t)c * 512 + g];
        float wb = gw1[(size_t)(66 + c) * 512 + g];
#pragma unroll
        for (int r = 0; r < 8; ++r) {
            a1[r] += feats[r][c] * wa;
            a2[r] += feats[r][c] * wb;
        }
    }
#pragma unroll
    for (int r = 0; r < 8; ++r) {
        P1[((size_t)(n * 64 + c0 + r)) * 512 + g] = a1[r];
        P2h[((size_t)(n * 64 + c0 + r)) * 512 + g] = (f16)a2[r];
    }
}

// ---------------------------------------------------------------------------
// Prep 2: Qc[n] = ques[n] @ W1c + b1; P1h = f16(P1 + Qc). Also zero Ctx.
// grid 64, block 512.
// ---------------------------------------------------------------------------
__global__ __launch_bounds__(512) void prep_q2(const float* __restrict__ ques,
                                               const float* __restrict__ gw1,
                                               const float* __restrict__ gb1,
                                               const float* __restrict__ P1,
                                               f16* __restrict__ P1h,
                                               float* __restrict__ Ctx) {
    const int n = blockIdx.x;
    const int t = threadIdx.x;
    __shared__ float q[256];
    if (t < 256) q[t] = ques[(size_t)n * 256 + t];
    __syncthreads();
    float acc = gb1[t];
    for (int e = 0; e < 256; ++e)
        acc += q[e] * gw1[(size_t)(132 + e) * 512 + t];
    const float* src = P1 + (((size_t)(n * 64)) << 9) + t;
    f16* dst = P1h + (((size_t)(n * 64)) << 9) + t;
    for (int r = 0; r < 64; ++r)
        dst[(size_t)r * 512] = (f16)(src[(size_t)r * 512] + acc);
    Ctx[(size_t)n * 512 + t] = 0.f;
}

// ---------------------------------------------------------------------------
// Prep 3: transpose W2/W3/W4 (512x512 fp32 [k][n] -> fp16 [n][k])
// ---------------------------------------------------------------------------
__global__ void transpose_w(const float* __restrict__ W2, const float* __restrict__ W3,
                            const float* __restrict__ W4, f16* __restrict__ T2,
                            f16* __restrict__ T3, f16* __restrict__ T4) {
    const int L = blockIdx.z;
    const float* W = (L == 0) ? W2 : ((L == 1) ? W3 : W4);
    f16* T = (L == 0) ? T2 : ((L == 1) ? T3 : T4);
    __shared__ float tile[32][33];
    const int bx = blockIdx.x * 32;  // n origin
    const int by = blockIdx.y * 32;  // k origin
    const int tx = threadIdx.x, ty = threadIdx.y;
    for (int r = ty; r < 32; r += 8)
        tile[r][tx] = W[(size_t)(by + r) * 512 + bx + tx];
    __syncthreads();
    for (int r = ty; r < 32; r += 8)
        T[(size_t)(bx + r) * 512 + by + tx] = (f16)tile[tx][r];
}

// ---------------------------------------------------------------------------
// Fused construct + layer-2 GEMM: C(256x128) = relu(H1tile @ T2 + b2) -> H2.
// A-tile rows = relu(P1h[nb,ii] + P2h[nb,jj]) built from F16 tables (2x16B
// loads + 8 f16 add/max per granule) into swizzled LDS slots (phys==linear p).
// B staged first via async16 so DMA overlaps the VALU construct.
// 256x128 / BK=64 / XCD-pinned. (256,2) ONLY: the 128-AGPR accumulator tile
// spills at 3 blocks/CU (round 10: VGPR 84, WRITE +80 MB scratch, 183 us).
// ---------------------------------------------------------------------------
__global__ __launch_bounds__(256, 2) void gemm2c(
    const f16* __restrict__ P1h, const f16* __restrict__ P2h,
    const f16* __restrict__ Bt, const float* __restrict__ bias,
    f16* __restrict__ Out, int row_base) {
    const int tid = threadIdx.x;
    const int lane = tid & 63;
    const int quad = lane >> 4;
    const int l15 = lane & 15;
    const int wv = tid >> 6;
    const int wm = wv >> 1, wn = wv & 1;
    const int b  = blockIdx.x;
    const int x  = b & 7;
    const int s  = b >> 3;
    const int bn = s & 3;
    const int bm = (s >> 2) * 8 + x;     // 0..255

    __shared__ alignas(16) f16 lA[256 * 64];   // 32 KB
    __shared__ alignas(16) f16 lB[128 * 64];   // 16 KB

    const int p0 = row_base + bm * 256;        // global pair index of row 0
    const int nb = p0 >> 12;                   // batch index
    const f16* P1b = P1h + (((size_t)(nb * 64)) << 9);
    const f16* P2b = P2h + (((size_t)(nb * 64)) << 9);

    f32x4 acc[8][4];
#pragma unroll
    for (int mi = 0; mi < 8; ++mi)
#pragma unroll
        for (int ni = 0; ni < 4; ++ni)
            acc[mi][ni] = (f32x4){0.f, 0.f, 0.f, 0.f};

    for (int kt = 0; kt < 8; ++kt) {
        const int k0 = kt * 64;
        // ---- stage B first (async DMA overlaps VALU construct below) ----
#pragma unroll
        for (int c = 0; c < 4; ++c) {
            int p = c * 256 + tid;
            int r = p >> 3;
            int gc = ((p & 7) - r) & 7;
            const f16* srcB = Bt + (((size_t)(bn * 128 + r)) << 9) + k0 + gc * 8;
            async16(srcB, &lB[(c * 256 + (tid & ~63)) * 8]);
        }
        // ---- construct A-tile granules (f16 adds) -> LDS ----
#pragma unroll
        for (int c = 0; c < 8; ++c) {
            int p = c * 256 + tid;
            int r = p >> 3;                       // row 0..255
            int gc = ((p & 7) - r) & 7;
            int k = k0 + gc * 8;
            int ii = ((bm * 4) + (r >> 6)) & 63;
            int jj = r & 63;
            half8 xx = *(const half8*)(P1b + (((size_t)ii) << 9) + k);
            half8 yy = *(const half8*)(P2b + (((size_t)jj) << 9) + k);
            half8 hv;
#pragma unroll
            for (int e = 0; e < 8; ++e) {
                f16 sv = (f16)(xx[e] + yy[e]);
                hv[e] = sv > (f16)0 ? sv : (f16)0;
            }
            *(half8*)&lA[p * 8] = hv;
        }
        __syncthreads();
#pragma unroll
        for (int ks = 0; ks < 2; ++ks) {
            half8 af[8], bf[4];
            const int gc = ks * 4 + quad;
#pragma unroll
            for (int mi = 0; mi < 8; ++mi) {
                int r = wm * 128 + mi * 16 + l15;
                af[mi] = *(const half8*)&lA[(r * 8 + ((gc + r) & 7)) * 8];
            }
#pragma unroll
            for (int ni = 0; ni < 4; ++ni) {
                int r = wn * 64 + ni * 16 + l15;
                bf[ni] = *(const half8*)&lB[(r * 8 + ((gc + r) & 7)) * 8];
            }
#pragma unroll
            for (int mi = 0; mi < 8; ++mi)
#pragma unroll
                for (int ni = 0; ni < 4; ++ni)
                    acc[mi][ni] = __builtin_amdgcn_mfma_f32_16x16x32_f16(
                        af[mi], bf[ni], acc[mi][ni], 0, 0, 0);
        }
        __syncthreads();
    }

#pragma unroll
    for (int mi = 0; mi < 8; ++mi) {
#pragma unroll
        for (int ni = 0; ni < 4; ++ni) {
            int col = bn * 128 + wn * 64 + ni * 16 + l15;
            float bb = bias[col];
#pragma unroll
            for (int rr = 0; rr < 4; ++rr) {
                int row = bm * 256 + wm * 128 + mi * 16 + quad * 4 + rr;
                float v = fmaxf(acc[mi][ni][rr] + bb, 0.f);
                Out[(((size_t)row) << 9) + col] = (f16)v;
            }
        }
    }
}

// ---------------------------------------------------------------------------
// GEMM (round-7-proven): C(256x128) = relu(A @ B + bias). 4 waves, wave-tile
// 128x64, BK=64, XCD-pinned. (256,2) ONLY — see gemm2c note (spills at 3).
// Granule swizzle: phys = r*8 + ((gc + r)&7); 2-way-max bank aliasing.
// REDUCE: shfl-butterfly row-sum of relu -> lsum -> Ctx atomics (mean num).
// ---------------------------------------------------------------------------
template <bool REDUCE>
__global__ __launch_bounds__(256, 2) void gemm_kernel(
    const f16* __restrict__ Ain, const f16* __restrict__ Bt,
    const float* __restrict__ bias, f16* __restrict__ Out,
    float* __restrict__ Ctx, int row_base) {
    const int tid = threadIdx.x;
    const int lane = tid & 63;
    const int quad = lane >> 4;
    const int l15 = lane & 15;
    const int wv = tid >> 6;
    const int wm = wv >> 1, wn = wv & 1;
    const int b  = blockIdx.x;
    const int x  = b & 7;
    const int s  = b >> 3;
    const int bn = s & 3;
    const int bm = (s >> 2) * 8 + x;     // 0..255

    __shared__ alignas(16) f16 lA[256 * 64];   // 32 KB
    __shared__ alignas(16) f16 lB[128 * 64];   // 16 KB
    __shared__ float lsum[128];

    if (REDUCE && tid < 128) lsum[tid] = 0.f;

    f32x4 acc[8][4];
#pragma unroll
    for (int mi = 0; mi < 8; ++mi)
#pragma unroll
        for (int ni = 0; ni < 4; ++ni)
            acc[mi][ni] = (f32x4){0.f, 0.f, 0.f, 0.f};

    for (int kt = 0; kt < 8; ++kt) {
        const int k0 = kt * 64;
#pragma unroll
        for (int c = 0; c < 8; ++c) {
            int p = c * 256 + tid;
            int r = p >> 3;
            int gc = ((p & 7) - r) & 7;
            const f16* srcA = Ain + (((size_t)(bm * 256 + r)) << 9) + k0 + gc * 8;
            async16(srcA, &lA[(c * 256 + (tid & ~63)) * 8]);
        }
#pragma unroll
        for (int c = 0; c < 4; ++c) {
            int p = c * 256 + tid;
            int r = p >> 3;
            int gc = ((p & 7) - r) & 7;
            const f16* srcB = Bt + (((size_t)(bn * 128 + r)) << 9) + k0 + gc * 8;
            async16(srcB, &lB[(c * 256 + (tid & ~63)) * 8]);
        }
        __syncthreads();
#pragma unroll
        for (int ks = 0; ks < 2; ++ks) {
            half8 af[8], bf[4];
            const int gc = ks * 4 + quad;
#pragma unroll
            for (int mi = 0; mi < 8; ++mi) {
                int r = wm * 128 + mi * 16 + l15;
                af[mi] = *(const half8*)&lA[(r * 8 + ((gc + r) & 7)) * 8];
            }
#pragma unroll
            for (int ni = 0; ni < 4; ++ni) {
                int r = wn * 64 + ni * 16 + l15;
                bf[ni] = *(const half8*)&lB[(r * 8 + ((gc + r) & 7)) * 8];
            }
#pragma unroll
            for (int mi = 0; mi < 8; ++mi)
#pragma unroll
                for (int ni = 0; ni < 4; ++ni)
                    acc[mi][ni] = __builtin_amdgcn_mfma_f32_16x16x32_f16(
                        af[mi], bf[ni], acc[mi][ni], 0, 0, 0);
        }
        __syncthreads();
    }

    if (!REDUCE) {
#pragma unroll
        for (int mi = 0; mi < 8; ++mi) {
#pragma unroll
            for (int ni = 0; ni < 4; ++ni) {
                int col = bn * 128 + wn * 64 + ni * 16 + l15;
                float bb = bias[col];
#pragma unroll
                for (int rr = 0; rr < 4; ++rr) {
                    int row = bm * 256 + wm * 128 + mi * 16 + quad * 4 + rr;
                    float v = fmaxf(acc[mi][ni][rr] + bb, 0.f);
                    Out[(((size_t)row) << 9) + col] = (f16)v;
                }
            }
        }
    } else {
#pragma unroll
        for (int ni = 0; ni < 4; ++ni) {
            int coll = wn * 64 + ni * 16 + l15;
            float bb = bias[bn * 128 + coll];
            float ssum = 0.f;
#pragma unroll
            for (int mi = 0; mi < 8; ++mi)
#pragma unroll
                for (int rr = 0; rr < 4; ++rr)
                    ssum += fmaxf(acc[mi][ni][rr] + bb, 0.f);
            ssum += __shfl_xor(ssum, 16, 64);
            ssum += __shfl_xor(ssum, 32, 64);
            if (quad == 0) atomicAdd(&lsum[coll], ssum);
        }
        __syncthreads();
        if (tid < 128) {
            int nb = (row_base + bm * 256) >> 12;
            atomicAdd(&Ctx[(((size_t)nb) << 9) + bn * 128 + tid], lsum[tid]);
        }
    }
}

// ---------------------------------------------------------------------------
// f-MLP layer: Out[n, cs*64..+64) = relu(In[n,:]*scale @ W + b).
// grid (64, 8) = 512 blocks, block 512 = 64 cols x 8 k-segments.
// ---------------------------------------------------------------------------
__global__ __launch_bounds__(512) void fmlp_layer(
    const float* __restrict__ In, const float* __restrict__ Wt,
    const float* __restrict__ bias, float* __restrict__ Out, float scale) {
    const int n = blockIdx.x, cs = blockIdx.y;
    const int t = threadIdx.x;
    const int col = cs * 64 + (t & 63);
    const int seg = t >> 6;
    __shared__ float a[512];
    __shared__ float red[512];
    a[t] = In[(size_t)n * 512 + t] * scale;
    __syncthreads();
    float p = 0.f;
#pragma unroll 8
    for (int i = seg * 64; i < seg * 64 + 64; ++i)
        p += a[i] * Wt[(size_t)i * 512 + col];
    red[t] = p;
    __syncthreads();
    if (t < 64) {
        float v = bias[col];
#pragma unroll
        for (int sg = 0; sg < 8; ++sg) v += red[sg * 64 + t];
        Out[(size_t)n * 512 + cs * 64 + t] = fmaxf(v, 0.f);
    }
}

// ---------------------------------------------------------------------------
// Final logits + log_softmax. grid 64, block 64 (one wave per batch row).
// ---------------------------------------------------------------------------
__global__ __launch_bounds__(64) void fmlp_out(
    const float* __restrict__ A2, const float* __restrict__ fw3,
    const float* __restrict__ fb3, float* __restrict__ out) {
    const int n = blockIdx.x;
    const int lane = threadIdx.x;
    float s0 = 0.f, s1 = 0.f;
    for (int i = lane; i < 512; i += 64) {
        float v = A2[(size_t)n * 512 + i];
        s0 += v * fw3[i * 2];
        s1 += v * fw3[i * 2 + 1];
    }
#pragma unroll
    for (int d = 1; d < 64; d <<= 1) {
        s0 += __shfl_xor(s0, d, 64);
        s1 += __shfl_xor(s1, d, 64);
    }
    if (lane == 0) {
        s0 += fb3[0];
        s1 += fb3[1];
        float m = fmaxf(s0, s1);
        float l = logf(expf(s0 - m) + expf(s1 - m)) + m;
        out[n * 2 + 0] = s0 - l;
        out[n * 2 + 1] = s1 - l;
    }
}

// ---------------------------------------------------------------------------
extern "C" void kernel_launch(void* const* d_in, const int* in_sizes, int n_in,
                              void* d_out, int out_size, void* d_ws, size_t ws_size,
                              hipStream_t stream) {
    const float* img  = (const float*)d_in[0];
    const float* ques = (const float*)d_in[1];
    const float* gw1  = (const float*)d_in[2];
    const float* gb1  = (const float*)d_in[3];
    const float* gw2  = (const float*)d_in[4];
    const float* gb2  = (const float*)d_in[5];
    const float* gw3  = (const float*)d_in[6];
    const float* gb3  = (const float*)d_in[7];
    const float* gw4  = (const float*)d_in[8];
    const float* gb4  = (const float*)d_in[9];
    const float* fw1  = (const float*)d_in[10];
    const float* fb1  = (const float*)d_in[11];
    const float* fw2  = (const float*)d_in[12];
    const float* fb2  = (const float*)d_in[13];
    const float* fw3  = (const float*)d_in[14];
    const float* fb3  = (const float*)d_in[15];

    char* ws = (char*)d_ws;
    size_t off = 0;
    float* P1  = (float*)(ws + off); off += (size_t)4096 * 512 * 4;   // 8 MB fp32 scratch
    f16* P1h = (f16*)(ws + off); off += (size_t)4096 * 512 * 2;       // 4 MB (P1+Qc, f16)
    f16* P2h = (f16*)(ws + off); off += (size_t)4096 * 512 * 2;       // 4 MB
    float* Ctx = (float*)(ws + off); off += (size_t)64 * 512 * 4;
    float* Z1  = (float*)(ws + off); off += (size_t)64 * 512 * 4;
    float* Z2  = (float*)(ws + off); off += (size_t)64 * 512 * 4;
    f16* T2 = (f16*)(ws + off); off += (size_t)512 * 512 * 2;
    f16* T3 = (f16*)(ws + off); off += (size_t)512 * 512 * 2;
    f16* T4 = (f16*)(ws + off); off += (size_t)512 * 512 * 2;
    const int MCH = 65536;                                            // rows/chunk
    f16* HA = (f16*)(ws + off); off += (size_t)MCH * 512 * 2;         // 67 MB
    f16* HB = (f16*)(ws + off); off += (size_t)MCH * 512 * 2;         // 67 MB

    prep_p12<<<512, 512, 0, stream>>>(img, gw1, P1, P2h);
    prep_q2<<<64, 512, 0, stream>>>(ques, gw1, gb1, P1, P1h, Ctx);
    transpose_w<<<dim3(16, 16, 3), dim3(32, 8), 0, stream>>>(gw2, gw3, gw4, T2, T3, T4);

    const int ggrid = (MCH / 256) * 4;       // 1024 blocks per GEMM dispatch
    for (int ch = 0; ch < 262144 / MCH; ++ch) {
        int row_base = ch * MCH;
        gemm2c<<<ggrid, 256, 0, stream>>>(P1h, P2h, T2, gb2, HB, row_base);
        gemm_kernel<false><<<ggrid, 256, 0, stream>>>(HB, T3, gb3, HA, nullptr, row_base);
        gemm_kernel<true ><<<ggrid, 256, 0, stream>>>(HA, T4, gb4, nullptr, Ctx, row_base);
    }

    fmlp_layer<<<dim3(64, 8), 512, 0, stream>>>(Ctx, fw1, fb1, Z1, 1.0f / 4096.0f);
    fmlp_layer<<<dim3(64, 8), 512, 0, stream>>>(Z1, fw2, fb2, Z2, 1.0f);
    fmlp_out<<<64, 64, 0, stream>>>(Z2, fw3, fb3, (float*)d_out);
}

// Round 12
// 564.178 us; speedup vs baseline: 2.2829x; 1.1676x over previous
//
#include <hip/hip_runtime.h>

typedef unsigned short u16;
typedef unsigned int u32;
typedef _Float16 f16;

using half8 = __attribute__((ext_vector_type(8))) _Float16;
using f32x4 = __attribute__((ext_vector_type(4))) float;

__device__ __forceinline__ void async16(const void* g, void* l) {
    __builtin_amdgcn_global_load_lds(
        (const __attribute__((address_space(1))) u32*)g,
        (__attribute__((address_space(3))) u32*)l, 16, 0, 0);
}

// ---------------------------------------------------------------------------
// Prep 1: P1 = feats @ W1a (fp32, Qc folded later), P2h = f16(feats @ W1b)
// ---------------------------------------------------------------------------
__global__ __launch_bounds__(512) void prep_p12(const float* __restrict__ img,
                                                const float* __restrict__ gw1,
                                                float* __restrict__ P1,
                                                f16* __restrict__ P2h) {
    const int blk = blockIdx.x;
    const int n = blk >> 3;
    const int c0 = (blk & 7) * 8;
    const int t = threadIdx.x;
    __shared__ float feats[8][68];
    for (int idx = t; idx < 8 * 66; idx += 512) {
        int rr = idx / 66, cc = idx % 66, cell = c0 + rr;
        float v;
        if (cc < 64)       v = img[((size_t)(n * 64 + cc)) * 64 + cell];
        else if (cc == 64) v = (float)(cell >> 3);
        else               v = (float)(cell & 7);
        feats[rr][cc] = v;
    }
    __syncthreads();
    const int g = t;
    float a1[8], a2[8];
#pragma unroll
    for (int r = 0; r < 8; ++r) { a1[r] = 0.f; a2[r] = 0.f; }
    for (int c = 0; c < 66; ++c) {
        float wa = gw1[(size_t)c * 512 + g];
        float wb = gw1[(size_t)(66 + c) * 512 + g];
#pragma unroll
        for (int r = 0; r < 8; ++r) {
            a1[r] += feats[r][c] * wa;
            a2[r] += feats[r][c] * wb;
        }
    }
#pragma unroll
    for (int r = 0; r < 8; ++r) {
        P1[((size_t)(n * 64 + c0 + r)) * 512 + g] = a1[r];
        P2h[((size_t)(n * 64 + c0 + r)) * 512 + g] = (f16)a2[r];
    }
}

// ---------------------------------------------------------------------------
// Prep 2: Qc[n] = ques[n] @ W1c + b1; P1h = f16(P1 + Qc). Also zero Ctx.
// grid 64, block 512.
// ---------------------------------------------------------------------------
__global__ __launch_bounds__(512) void prep_q2(const float* __restrict__ ques,
                                               const float* __restrict__ gw1,
                                               const float* __restrict__ gb1,
                                               const float* __restrict__ P1,
                                               f16* __restrict__ P1h,
                                               float* __restrict__ Ctx) {
    const int n = blockIdx.x;
    const int t = threadIdx.x;
    __shared__ float q[256];
    if (t < 256) q[t] = ques[(size_t)n * 256 + t];
    __syncthreads();
    float acc = gb1[t];
    for (int e = 0; e < 256; ++e)
        acc += q[e] * gw1[(size_t)(132 + e) * 512 + t];
    const float* src = P1 + (((size_t)(n * 64)) << 9) + t;
    f16* dst = P1h + (((size_t)(n * 64)) << 9) + t;
    for (int r = 0; r < 64; ++r)
        dst[(size_t)r * 512] = (f16)(src[(size_t)r * 512] + acc);
    Ctx[(size_t)n * 512 + t] = 0.f;
}

// ---------------------------------------------------------------------------
// Prep 3: transpose W2/W3/W4 (512x512 fp32 [k][n] -> fp16 [n][k])
// ---------------------------------------------------------------------------
__global__ void transpose_w(const float* __restrict__ W2, const float* __restrict__ W3,
                            const float* __restrict__ W4, f16* __restrict__ T2,
                            f16* __restrict__ T3, f16* __restrict__ T4) {
    const int L = blockIdx.z;
    const float* W = (L == 0) ? W2 : ((L == 1) ? W3 : W4);
    f16* T = (L == 0) ? T2 : ((L == 1) ? T3 : T4);
    __shared__ float tile[32][33];
    const int bx = blockIdx.x * 32;  // n origin
    const int by = blockIdx.y * 32;  // k origin
    const int tx = threadIdx.x, ty = threadIdx.y;
    for (int r = ty; r < 32; r += 8)
        tile[r][tx] = W[(size_t)(by + r) * 512 + bx + tx];
    __syncthreads();
    for (int r = ty; r < 32; r += 8)
        T[(size_t)(bx + r) * 512 + by + tx] = (f16)tile[tx][r];
}

// ---------------------------------------------------------------------------
// Fused construct + layer-2 GEMM v2: C(256x128) = relu(H1tile @ T2 + b2).
// DOUBLE-BUFFERED at BK=32 (lA 2x16KB + lB 2x8KB = 48 KB, 2 blocks/CU):
// iteration kt stages B(kt+1) via async16 and CONSTRUCTS A(kt+1) with packed
// f16 VALU into buf^1 while MFMA(kt) runs on buf — construct leaves the
// critical path (m114: MFMA+VALU pipes co-issue). One barrier per kt.
// BK=32 granule swizzle (rounds 2-6 proven, 0 conflicts):
//   phys = r*4 + ((g + (r>>1)) & 3); staging decode g = ((p&3)-(r>>1))&3.
// (256,2) ONLY: 128-AGPR acc spills at 3 blocks/CU (round 10).
// ---------------------------------------------------------------------------
__global__ __launch_bounds__(256, 2) void gemm2c(
    const f16* __restrict__ P1h, const f16* __restrict__ P2h,
    const f16* __restrict__ Bt, const float* __restrict__ bias,
    f16* __restrict__ Out, int row_base) {
    const int tid = threadIdx.x;
    const int lane = tid & 63;
    const int quad = lane >> 4;
    const int l15 = lane & 15;
    const int wv = tid >> 6;
    const int wm = wv >> 1, wn = wv & 1;
    const int b  = blockIdx.x;
    const int x  = b & 7;
    const int s  = b >> 3;
    const int bn = s & 3;
    const int bm = (s >> 2) * 8 + x;     // 0..255

    __shared__ alignas(16) f16 lA[2][256 * 32];   // 2 x 16 KB
    __shared__ alignas(16) f16 lB[2][128 * 32];   // 2 x  8 KB

    const int p0 = row_base + bm * 256;
    const int nb = p0 >> 12;
    const f16* P1b = P1h + (((size_t)(nb * 64)) << 9);
    const f16* P2b = P2h + (((size_t)(nb * 64)) << 9);

    // ---- helpers as lambdas ----
    auto stageB = [&](int kt, int buf) {
#pragma unroll
        for (int c = 0; c < 2; ++c) {
            int p = c * 256 + tid;
            int r = p >> 2;
            int g = ((p & 3) - (r >> 1)) & 3;
            const f16* srcB = Bt + (((size_t)(bn * 128 + r)) << 9) + kt * 32 + g * 8;
            async16(srcB, &lB[buf][(c * 256 + (tid & ~63)) * 8]);
        }
    };
    auto constructA = [&](int kt, int buf) {
#pragma unroll
        for (int c = 0; c < 4; ++c) {
            int p = c * 256 + tid;
            int r = p >> 2;                       // row 0..255
            int g = ((p & 3) - (r >> 1)) & 3;
            int k = kt * 32 + g * 8;
            int ii = ((bm * 4) + (r >> 6)) & 63;
            int jj = r & 63;
            half8 xx = *(const half8*)(P1b + (((size_t)ii) << 9) + k);
            half8 yy = *(const half8*)(P2b + (((size_t)jj) << 9) + k);
            half8 sv = xx + yy;                           // v_pk_add_f16 x4
            sv = __builtin_elementwise_max(sv, (half8)(f16)0.f);  // v_pk_max_f16 x4
            *(half8*)&lA[buf][p * 8] = sv;
        }
    };

    f32x4 acc[8][4];
#pragma unroll
    for (int mi = 0; mi < 8; ++mi)
#pragma unroll
        for (int ni = 0; ni < 4; ++ni)
            acc[mi][ni] = (f32x4){0.f, 0.f, 0.f, 0.f};

    // prologue: fill buffer 0
    stageB(0, 0);
    constructA(0, 0);
    __syncthreads();

    for (int kt = 0; kt < 16; ++kt) {
        const int cur = kt & 1;
        // stage next tile into the other buffer (B DMA first, then VALU A)
        if (kt < 15) {
            stageB(kt + 1, cur ^ 1);
            constructA(kt + 1, cur ^ 1);
        }
        // MFMA on current buffer (independent of staging above -> co-issue)
        half8 af[8], bf[4];
#pragma unroll
        for (int mi = 0; mi < 8; ++mi) {
            int r = wm * 128 + mi * 16 + l15;
            af[mi] = *(const half8*)&lA[cur][(r * 4 + ((quad + (r >> 1)) & 3)) * 8];
        }
#pragma unroll
        for (int ni = 0; ni < 4; ++ni) {
            int r = wn * 64 + ni * 16 + l15;
            bf[ni] = *(const half8*)&lB[cur][(r * 4 + ((quad + (r >> 1)) & 3)) * 8];
        }
#pragma unroll
        for (int mi = 0; mi < 8; ++mi)
#pragma unroll
            for (int ni = 0; ni < 4; ++ni)
                acc[mi][ni] = __builtin_amdgcn_mfma_f32_16x16x32_f16(
                    af[mi], bf[ni], acc[mi][ni], 0, 0, 0);
        __syncthreads();   // next buffer complete for all; cur free for reuse
    }

#pragma unroll
    for (int mi = 0; mi < 8; ++mi) {
#pragma unroll
        for (int ni = 0; ni < 4; ++ni) {
            int col = bn * 128 + wn * 64 + ni * 16 + l15;
            float bb = bias[col];
#pragma unroll
            for (int rr = 0; rr < 4; ++rr) {
                int row = bm * 256 + wm * 128 + mi * 16 + quad * 4 + rr;
                float v = fmaxf(acc[mi][ni][rr] + bb, 0.f);
                Out[(((size_t)row) << 9) + col] = (f16)v;
            }
        }
    }
}

// ---------------------------------------------------------------------------
// GEMM (round-7-proven): C(256x128) = relu(A @ B + bias). 4 waves, wave-tile
// 128x64, BK=64, XCD-pinned. (256,2) ONLY — 128-AGPR acc spills at 3 blk/CU.
// Granule swizzle: phys = r*8 + ((gc + r)&7); 2-way-max bank aliasing.
// REDUCE: shfl-butterfly row-sum of relu -> lsum -> Ctx atomics (mean num).
// ---------------------------------------------------------------------------
template <bool REDUCE>
__global__ __launch_bounds__(256, 2) void gemm_kernel(
    const f16* __restrict__ Ain, const f16* __restrict__ Bt,
    const float* __restrict__ bias, f16* __restrict__ Out,
    float* __restrict__ Ctx, int row_base) {
    const int tid = threadIdx.x;
    const int lane = tid & 63;
    const int quad = lane >> 4;
    const int l15 = lane & 15;
    const int wv = tid >> 6;
    const int wm = wv >> 1, wn = wv & 1;
    const int b  = blockIdx.x;
    const int x  = b & 7;
    const int s  = b >> 3;
    const int bn = s & 3;
    const int bm = (s >> 2) * 8 + x;     // 0..255

    __shared__ alignas(16) f16 lA[256 * 64];   // 32 KB
    __shared__ alignas(16) f16 lB[128 * 64];   // 16 KB
    __shared__ float lsum[128];

    if (REDUCE && tid < 128) lsum[tid] = 0.f;

    f32x4 acc[8][4];
#pragma unroll
    for (int mi = 0; mi < 8; ++mi)
#pragma unroll
        for (int ni = 0; ni < 4; ++ni)
            acc[mi][ni] = (f32x4){0.f, 0.f, 0.f, 0.f};

    for (int kt = 0; kt < 8; ++kt) {
        const int k0 = kt * 64;
#pragma unroll
        for (int c = 0; c < 8; ++c) {
            int p = c * 256 + tid;
            int r = p >> 3;
            int gc = ((p & 7) - r) & 7;
            const f16* srcA = Ain + (((size_t)(bm * 256 + r)) << 9) + k0 + gc * 8;
            async16(srcA, &lA[(c * 256 + (tid & ~63)) * 8]);
        }
#pragma unroll
        for (int c = 0; c < 4; ++c) {
            int p = c * 256 + tid;
            int r = p >> 3;
            int gc = ((p & 7) - r) & 7;
            const f16* srcB = Bt + (((size_t)(bn * 128 + r)) << 9) + k0 + gc * 8;
            async16(srcB, &lB[(c * 256 + (tid & ~63)) * 8]);
        }
        __syncthreads();
#pragma unroll
        for (int ks = 0; ks < 2; ++ks) {
            half8 af[8], bf[4];
            const int gc = ks * 4 + quad;
#pragma unroll
            for (int mi = 0; mi < 8; ++mi) {
                int r = wm * 128 + mi * 16 + l15;
                af[mi] = *(const half8*)&lA[(r * 8 + ((gc + r) & 7)) * 8];
            }
#pragma unroll
            for (int ni = 0; ni < 4; ++ni) {
                int r = wn * 64 + ni * 16 + l15;
                bf[ni] = *(const half8*)&lB[(r * 8 + ((gc + r) & 7)) * 8];
            }
#pragma unroll
            for (int mi = 0; mi < 8; ++mi)
#pragma unroll
                for (int ni = 0; ni < 4; ++ni)
                    acc[mi][ni] = __builtin_amdgcn_mfma_f32_16x16x32_f16(
                        af[mi], bf[ni], acc[mi][ni], 0, 0, 0);
        }
        __syncthreads();
    }

    if (!REDUCE) {
#pragma unroll
        for (int mi = 0; mi < 8; ++mi) {
#pragma unroll
            for (int ni = 0; ni < 4; ++ni) {
                int col = bn * 128 + wn * 64 + ni * 16 + l15;
                float bb = bias[col];
#pragma unroll
                for (int rr = 0; rr < 4; ++rr) {
                    int row = bm * 256 + wm * 128 + mi * 16 + quad * 4 + rr;
                    float v = fmaxf(acc[mi][ni][rr] + bb, 0.f);
                    Out[(((size_t)row) << 9) + col] = (f16)v;
                }
            }
        }
    } else {
#pragma unroll
        for (int ni = 0; ni < 4; ++ni) {
            int coll = wn * 64 + ni * 16 + l15;
            float bb = bias[bn * 128 + coll];
            float ssum = 0.f;
#pragma unroll
            for (int mi = 0; mi < 8; ++mi)
#pragma unroll
                for (int rr = 0; rr < 4; ++rr)
                    ssum += fmaxf(acc[mi][ni][rr] + bb, 0.f);
            ssum += __shfl_xor(ssum, 16, 64);
            ssum += __shfl_xor(ssum, 32, 64);
            if (quad == 0) atomicAdd(&lsum[coll], ssum);
        }
        __syncthreads();
        if (tid < 128) {
            int nb = (row_base + bm * 256) >> 12;
            atomicAdd(&Ctx[(((size_t)nb) << 9) + bn * 128 + tid], lsum[tid]);
        }
    }
}

// ---------------------------------------------------------------------------
// f-MLP layer: Out[n, cs*64..+64) = relu(In[n,:]*scale @ W + b).
// grid (64, 8) = 512 blocks, block 512 = 64 cols x 8 k-segments.
// ---------------------------------------------------------------------------
__global__ __launch_bounds__(512) void fmlp_layer(
    const float* __restrict__ In, const float* __restrict__ Wt,
    const float* __restrict__ bias, float* __restrict__ Out, float scale) {
    const int n = blockIdx.x, cs = blockIdx.y;
    const int t = threadIdx.x;
    const int col = cs * 64 + (t & 63);
    const int seg = t >> 6;
    __shared__ float a[512];
    __shared__ float red[512];
    a[t] = In[(size_t)n * 512 + t] * scale;
    __syncthreads();
    float p = 0.f;
#pragma unroll 8
    for (int i = seg * 64; i < seg * 64 + 64; ++i)
        p += a[i] * Wt[(size_t)i * 512 + col];
    red[t] = p;
    __syncthreads();
    if (t < 64) {
        float v = bias[col];
#pragma unroll
        for (int sg = 0; sg < 8; ++sg) v += red[sg * 64 + t];
        Out[(size_t)n * 512 + cs * 64 + t] = fmaxf(v, 0.f);
    }
}

// ---------------------------------------------------------------------------
// Final logits + log_softmax. grid 64, block 64 (one wave per batch row).
// ---------------------------------------------------------------------------
__global__ __launch_bounds__(64) void fmlp_out(
    const float* __restrict__ A2, const float* __restrict__ fw3,
    const float* __restrict__ fb3, float* __restrict__ out) {
    const int n = blockIdx.x;
    const int lane = threadIdx.x;
    float s0 = 0.f, s1 = 0.f;
    for (int i = lane; i < 512; i += 64) {
        float v = A2[(size_t)n * 512 + i];
        s0 += v * fw3[i * 2];
        s1 += v * fw3[i * 2 + 1];
    }
#pragma unroll
    for (int d = 1; d < 64; d <<= 1) {
        s0 += __shfl_xor(s0, d, 64);
        s1 += __shfl_xor(s1, d, 64);
    }
    if (lane == 0) {
        s0 += fb3[0];
        s1 += fb3[1];
        float m = fmaxf(s0, s1);
        float l = logf(expf(s0 - m) + expf(s1 - m)) + m;
        out[n * 2 + 0] = s0 - l;
        out[n * 2 + 1] = s1 - l;
    }
}

// ---------------------------------------------------------------------------
extern "C" void kernel_launch(void* const* d_in, const int* in_sizes, int n_in,
                              void* d_out, int out_size, void* d_ws, size_t ws_size,
                              hipStream_t stream) {
    const float* img  = (const float*)d_in[0];
    const float* ques = (const float*)d_in[1];
    const float* gw1  = (const float*)d_in[2];
    const float* gb1  = (const float*)d_in[3];
    const float* gw2  = (const float*)d_in[4];
    const float* gb2  = (const float*)d_in[5];
    const float* gw3  = (const float*)d_in[6];
    const float* gb3  = (const float*)d_in[7];
    const float* gw4  = (const float*)d_in[8];
    const float* gb4  = (const float*)d_in[9];
    const float* fw1  = (const float*)d_in[10];
    const float* fb1  = (const float*)d_in[11];
    const float* fw2  = (const float*)d_in[12];
    const float* fb2  = (const float*)d_in[13];
    const float* fw3  = (const float*)d_in[14];
    const float* fb3  = (const float*)d_in[15];

    char* ws = (char*)d_ws;
    size_t off = 0;
    float* P1  = (float*)(ws + off); off += (size_t)4096 * 512 * 4;   // 8 MB fp32 scratch
    f16* P1h = (f16*)(ws + off); off += (size_t)4096 * 512 * 2;       // 4 MB (P1+Qc, f16)
    f16* P2h = (f16*)(ws + off); off += (size_t)4096 * 512 * 2;       // 4 MB
    float* Ctx = (float*)(ws + off); off += (size_t)64 * 512 * 4;
    float* Z1  = (float*)(ws + off); off += (size_t)64 * 512 * 4;
    float* Z2  = (float*)(ws + off); off += (size_t)64 * 512 * 4;
    f16* T2 = (f16*)(ws + off); off += (size_t)512 * 512 * 2;
    f16* T3 = (f16*)(ws + off); off += (size_t)512 * 512 * 2;
    f16* T4 = (f16*)(ws + off); off += (size_t)512 * 512 * 2;
    const int MCH = 65536;                                            // rows/chunk
    f16* HA = (f16*)(ws + off); off += (size_t)MCH * 512 * 2;         // 67 MB
    f16* HB = (f16*)(ws + off); off += (size_t)MCH * 512 * 2;         // 67 MB

    prep_p12<<<512, 512, 0, stream>>>(img, gw1, P1, P2h);
    prep_q2<<<64, 512, 0, stream>>>(ques, gw1, gb1, P1, P1h, Ctx);
    transpose_w<<<dim3(16, 16, 3), dim3(32, 8), 0, stream>>>(gw2, gw3, gw4, T2, T3, T4);

    const int ggrid = (MCH / 256) * 4;       // 1024 blocks per GEMM dispatch
    for (int ch = 0; ch < 262144 / MCH; ++ch) {
        int row_base = ch * MCH;
        gemm2c<<<ggrid, 256, 0, stream>>>(P1h, P2h, T2, gb2, HB, row_base);
        gemm_kernel<false><<<ggrid, 256, 0, stream>>>(HB, T3, gb3, HA, nullptr, row_base);
        gemm_kernel<true ><<<ggrid, 256, 0, stream>>>(HA, T4, gb4, nullptr, Ctx, row_base);
    }

    fmlp_layer<<<dim3(64, 8), 512, 0, stream>>>(Ctx, fw1, fb1, Z1, 1.0f / 4096.0f);
    fmlp_layer<<<dim3(64, 8), 512, 0, stream>>>(Z1, fw2, fb2, Z2, 1.0f);
    fmlp_out<<<64, 64, 0, stream>>>(Z2, fw3, fb3, (float*)d_out);
}